// Round 1
// baseline (541.855 us; speedup 1.0000x reference)
//
#include <hip/hip_runtime.h>
#include <math.h>

#define BB 16
#define DMODEL 2048
#define NHEAD 32
#define SKV 4096
#define HDIM 64
#define BH (BB*NHEAD) /* 512 */

// ---------------------------------------------------------------------------
// init: q/k/v <- bias, attn <- 0, out_vec <- bo   (5 regions x 32768 floats)
// ---------------------------------------------------------------------------
__global__ __launch_bounds__(256) void init_k(
    const float* __restrict__ bq, const float* __restrict__ bk,
    const float* __restrict__ bv, const float* __restrict__ bo,
    float* __restrict__ q, float* __restrict__ k, float* __restrict__ v,
    float* __restrict__ attn, float* __restrict__ out) {
  int idx = blockIdx.x * 256 + threadIdx.x;
  int region = idx >> 15;       // /32768
  int r = idx & 32767;
  int o = r & (DMODEL - 1);
  switch (region) {
    case 0: q[r] = bq[o]; break;
    case 1: k[r] = bk[o]; break;
    case 2: v[r] = bv[o]; break;
    case 3: attn[r] = 0.f; break;
    case 4: out[r] = bo[o]; break;
  }
}

// ---------------------------------------------------------------------------
// partial GEMM: dst[b][o] += sum_{i in tile} src[b][i] * W[i][o]
// grid: (DMODEL/256, DMODEL/256, nmat). dst pre-initialized with bias.
// ---------------------------------------------------------------------------
__global__ __launch_bounds__(256) void gemm16_part(
    const float* __restrict__ src,
    const float* __restrict__ Wa, const float* __restrict__ Wb,
    const float* __restrict__ Wc,
    float* __restrict__ da, float* __restrict__ db, float* __restrict__ dc) {
  const float* W = (blockIdx.z == 0) ? Wa : ((blockIdx.z == 1) ? Wb : Wc);
  float* dst     = (blockIdx.z == 0) ? da : ((blockIdx.z == 1) ? db : dc);
  __shared__ float xs[16][256];
  int o  = blockIdx.x * 256 + threadIdx.x;
  int i0 = blockIdx.y * 256;
  for (int t = threadIdx.x; t < 16 * 256; t += 256) {
    int b = t >> 8, i = t & 255;
    xs[b][i] = src[b * DMODEL + i0 + i];
  }
  __syncthreads();
  float acc[16];
#pragma unroll
  for (int b = 0; b < 16; ++b) acc[b] = 0.f;
#pragma unroll 4
  for (int i = 0; i < 256; ++i) {
    float w = W[(size_t)(i0 + i) * DMODEL + o];
#pragma unroll
    for (int b = 0; b < 16; ++b) acc[b] = fmaf(xs[b][i], w, acc[b]);
  }
#pragma unroll
  for (int b = 0; b < 16; ++b) atomicAdd(&dst[b * DMODEL + o], acc[b]);
}

// ---------------------------------------------------------------------------
// K copy + scores. One block = 256 rows of one (b,h). wave: 4 rows x 16 lanes
// x float4. Replaces row last_pos[b] with new k. scores[j] = q.k / 8.
// ---------------------------------------------------------------------------
__global__ __launch_bounds__(256) void k_copy_scores(
    const float* __restrict__ cacheK, const float* __restrict__ knew,
    const float* __restrict__ qv, const int* __restrict__ last_pos,
    float* __restrict__ outK, float* __restrict__ scores) {
  int bh = blockIdx.x >> 4;           // 16 blocks per (b,h)
  int j0 = (blockIdx.x & 15) << 8;    // 256 rows per block
  int b = bh >> 5;
  int lp = last_pos[b];
  int tid = threadIdx.x;
  int wave = tid >> 6, lane = tid & 63, q4 = lane >> 4, l16 = lane & 15;
  const float4 qf = ((const float4*)(qv + bh * HDIM))[l16];
  const float4* K4 = (const float4*)cacheK;
  float4* O4 = (float4*)outK;
  const float4* KN = (const float4*)(knew + bh * HDIM);
  float* s = scores + (size_t)bh * SKV;
  for (int r = wave * 4 + q4; r < 256; r += 16) {
    int j = j0 + r;
    size_t off = ((size_t)bh * SKV + j) * 16 + l16;
    float4 kv = K4[off];
    if (j == lp) kv = KN[l16];
    O4[off] = kv;
    float p = qf.x * kv.x + qf.y * kv.y + qf.z * kv.z + qf.w * kv.w;
    p += __shfl_xor(p, 1);
    p += __shfl_xor(p, 2);
    p += __shfl_xor(p, 4);
    p += __shfl_xor(p, 8);
    if (l16 == 0 && j <= lp) s[j] = p * 0.125f;
  }
}

// ---------------------------------------------------------------------------
// softmax over scores[bh][0..last_pos] in place; blocks < 128 also zero attn.
// ---------------------------------------------------------------------------
__global__ __launch_bounds__(256) void softmax_k(
    float* __restrict__ scores, const int* __restrict__ last_pos) {
  int bh = blockIdx.x;
  int b = bh >> 5;
  int n = last_pos[b] + 1;
  float* s = scores + (size_t)bh * SKV;
  int tid = threadIdx.x;
  __shared__ float red[4], red2[4];
  float m = -1e30f;
  for (int j = tid; j < n; j += 256) m = fmaxf(m, s[j]);
#pragma unroll
  for (int o = 1; o < 64; o <<= 1) m = fmaxf(m, __shfl_xor(m, o));
  if ((tid & 63) == 0) red[tid >> 6] = m;
  __syncthreads();
  m = fmaxf(fmaxf(red[0], red[1]), fmaxf(red[2], red[3]));
  float sum = 0.f;
  for (int j = tid; j < n; j += 256) {
    float e = __expf(s[j] - m);
    s[j] = e;
    sum += e;
  }
#pragma unroll
  for (int o = 1; o < 64; o <<= 1) sum += __shfl_xor(sum, o);
  if ((tid & 63) == 0) red2[tid >> 6] = sum;
  __syncthreads();
  sum = red2[0] + red2[1] + red2[2] + red2[3];
  float inv = 1.f / sum;
  for (int j = tid; j < n; j += 256) s[j] *= inv;
}

// ---------------------------------------------------------------------------
// V copy + PV accumulate. Same layout as k_copy_scores; per-block partial of
// sum_j p_j * v_j reduced in wave+LDS, one atomicAdd per dim.
// ---------------------------------------------------------------------------
__global__ __launch_bounds__(256) void v_copy_pv(
    const float* __restrict__ cacheV, const float* __restrict__ vnew,
    const float* __restrict__ probs, const int* __restrict__ last_pos,
    float* __restrict__ outV, float* __restrict__ attn) {
  __shared__ float part[4][64];
  int bh = blockIdx.x >> 4;
  int j0 = (blockIdx.x & 15) << 8;
  int b = bh >> 5;
  int lp = last_pos[b];
  int tid = threadIdx.x;
  int wave = tid >> 6, lane = tid & 63, q4 = lane >> 4, l16 = lane & 15;
  const float4* V4 = (const float4*)cacheV;
  float4* O4 = (float4*)outV;
  const float4* VN = (const float4*)(vnew + bh * HDIM);
  const float* pr = probs + (size_t)bh * SKV;
  float4 acc = {0.f, 0.f, 0.f, 0.f};
  for (int r = wave * 4 + q4; r < 256; r += 16) {
    int j = j0 + r;
    size_t off = ((size_t)bh * SKV + j) * 16 + l16;
    float4 vv = V4[off];
    if (j == lp) vv = VN[l16];
    O4[off] = vv;
    if (j <= lp) {
      float p = pr[j];
      acc.x = fmaf(p, vv.x, acc.x);
      acc.y = fmaf(p, vv.y, acc.y);
      acc.z = fmaf(p, vv.z, acc.z);
      acc.w = fmaf(p, vv.w, acc.w);
    }
  }
  // reduce the 4 quarter-groups of each wave (lanes differing in bits 4,5)
  acc.x += __shfl_xor(acc.x, 16); acc.x += __shfl_xor(acc.x, 32);
  acc.y += __shfl_xor(acc.y, 16); acc.y += __shfl_xor(acc.y, 32);
  acc.z += __shfl_xor(acc.z, 16); acc.z += __shfl_xor(acc.z, 32);
  acc.w += __shfl_xor(acc.w, 16); acc.w += __shfl_xor(acc.w, 32);
  if (q4 == 0) ((float4*)part[wave])[l16] = acc;
  __syncthreads();
  if (tid < 64) {
    float v0 = part[0][tid] + part[1][tid] + part[2][tid] + part[3][tid];
    atomicAdd(&attn[bh * HDIM + tid], v0);
  }
}

// ---------------------------------------------------------------------------
extern "C" void kernel_launch(void* const* d_in, const int* in_sizes, int n_in,
                              void* d_out, int out_size, void* d_ws, size_t ws_size,
                              hipStream_t stream) {
  const float* x       = (const float*)d_in[0];
  const int*   last_pos= (const int*)d_in[1];
  // d_in[2] = mask, recomputed from last_pos, ignored
  const float* Wq = (const float*)d_in[3];
  const float* bq = (const float*)d_in[4];
  const float* Wk = (const float*)d_in[5];
  const float* bk = (const float*)d_in[6];
  const float* Wv = (const float*)d_in[7];
  const float* bv = (const float*)d_in[8];
  const float* Wo = (const float*)d_in[9];
  const float* bo = (const float*)d_in[10];
  const float* cacheK = (const float*)d_in[11];
  const float* cacheV = (const float*)d_in[12];

  float* out  = (float*)d_out;                       // 32768
  float* outK = out + (size_t)BB * DMODEL;           // 134217728
  float* outV = outK + (size_t)BH * SKV * HDIM;      // 134217728

  float* ws     = (float*)d_ws;
  float* q      = ws;                                // 32768
  float* k      = ws + 32768;                        // 32768
  float* v      = ws + 65536;                        // 32768
  float* scores = ws + 98304;                        // BH*SKV = 2097152
  float* attn   = ws + 98304 + (size_t)BH * SKV;     // 32768

  init_k<<<640, 256, 0, stream>>>(bq, bk, bv, bo, q, k, v, attn, out);
  gemm16_part<<<dim3(8, 8, 3), 256, 0, stream>>>(x, Wq, Wk, Wv, q, k, v);
  k_copy_scores<<<8192, 256, 0, stream>>>(cacheK, k, q, last_pos, outK, scores);
  softmax_k<<<512, 256, 0, stream>>>(scores, last_pos);
  v_copy_pv<<<8192, 256, 0, stream>>>(cacheV, v, scores, last_pos, outV, attn);
  gemm16_part<<<dim3(8, 8, 1), 256, 0, stream>>>(attn, Wo, Wo, Wo, out, out, out);
}

// Round 3
// 458.129 us; speedup vs baseline: 1.1828x; 1.1828x over previous
//
#include <hip/hip_runtime.h>
#include <math.h>

#define BB 16
#define DMODEL 2048
#define NHEAD 32
#define SKV 4096
#define HDIM 64
#define BH (BB*NHEAD) /* 512 */

typedef float f4 __attribute__((ext_vector_type(4)));

// ---------------------------------------------------------------------------
// partial GEMM, no atomics: part[tile_y][b][o] = sum_{i in tile} src[b][i]*W[i][o]
// grid (2, DMODEL/rows, nmat), block 256. Each thread owns 4 consecutive
// o-columns (float4 weight loads, wave covers 1KB contiguous per row).
// ---------------------------------------------------------------------------
__global__ __launch_bounds__(256) void gemm_part(
    const float* __restrict__ src,
    const float* __restrict__ Wa, const float* __restrict__ Wb,
    const float* __restrict__ Wc,
    float* __restrict__ pa, float* __restrict__ pb, float* __restrict__ pc,
    int rows) {
  const float* W = (blockIdx.z == 0) ? Wa : ((blockIdx.z == 1) ? Wb : Wc);
  float* part    = (blockIdx.z == 0) ? pa : ((blockIdx.z == 1) ? pb : pc);
  __shared__ float xs[16][64];
  int tid = threadIdx.x;
  int i0 = blockIdx.y * rows;
  int o  = blockIdx.x * 1024 + tid * 4;
  int nx = 16 * rows;
  for (int t = tid * 4; t < nx; t += 1024) {
    int b = t / rows, i = t - b * rows;
    *(f4*)&xs[b][i] = *(const f4*)&src[b * DMODEL + i0 + i];
  }
  __syncthreads();
  f4 acc[16];
#pragma unroll
  for (int b = 0; b < 16; ++b) acc[b] = (f4)0.f;
#pragma unroll 4
  for (int i = 0; i < rows; ++i) {
    f4 w = *(const f4*)&W[(size_t)(i0 + i) * DMODEL + o];
#pragma unroll
    for (int b = 0; b < 16; ++b) {
      float xv = xs[b][i];
      acc[b] += xv * w;
    }
  }
  float* p = part + (size_t)blockIdx.y * (16 * DMODEL) + o;
#pragma unroll
  for (int b = 0; b < 16; ++b) *(f4*)&p[b * DMODEL] = acc[b];
}

// ---------------------------------------------------------------------------
// reduce partials over tiles + bias -> dst.  grid (32768/256, nmat)
// ---------------------------------------------------------------------------
__global__ __launch_bounds__(256) void gemm_reduce(
    const float* __restrict__ pa, const float* __restrict__ pb,
    const float* __restrict__ pc,
    const float* __restrict__ ba, const float* __restrict__ bb,
    const float* __restrict__ bc,
    float* __restrict__ da, float* __restrict__ db, float* __restrict__ dc,
    int ntiles) {
  const float* p    = (blockIdx.y == 0) ? pa : ((blockIdx.y == 1) ? pb : pc);
  const float* bias = (blockIdx.y == 0) ? ba : ((blockIdx.y == 1) ? bb : bc);
  float* dst        = (blockIdx.y == 0) ? da : ((blockIdx.y == 1) ? db : dc);
  int idx = blockIdx.x * 256 + threadIdx.x;
  float s = bias[idx & (DMODEL - 1)];
#pragma unroll 8
  for (int t = 0; t < ntiles; ++t) s += p[(size_t)t * (16 * DMODEL) + idx];
  dst[idx] = s;
}

// ---------------------------------------------------------------------------
// K copy + scores. Block = 256 rows of one (b,h); wave = 4 rows x 16 lanes x
// float4; 16 statically-unrolled iterations -> 16 loads in flight.
// ---------------------------------------------------------------------------
__global__ __launch_bounds__(256) void k_copy_scores(
    const float* __restrict__ cacheK, const float* __restrict__ knew,
    const float* __restrict__ qv, const int* __restrict__ last_pos,
    float* __restrict__ outK, float* __restrict__ scores) {
  int bh = blockIdx.x >> 4;
  int j0 = (blockIdx.x & 15) << 8;
  int b = bh >> 5;
  int lp = last_pos[b];
  int tid = threadIdx.x;
  int wave = tid >> 6, lane = tid & 63, q4 = lane >> 4, l16 = lane & 15;
  int rbase = wave * 4 + q4;
  const f4 qf = ((const f4*)(qv + bh * HDIM))[l16];
  const f4 kn = ((const f4*)(knew + bh * HDIM))[l16];
  size_t base = ((size_t)bh * SKV + j0 + rbase) * 16 + l16;
  const f4* K4 = (const f4*)cacheK + base;
  f4* O4 = (f4*)outK + base;
  float* s = scores + (size_t)bh * SKV;
#pragma unroll
  for (int t = 0; t < 16; ++t) {
    int j = j0 + rbase + t * 16;
    f4 kv = __builtin_nontemporal_load(&K4[t * 256]);
    if (j == lp) kv = kn;
    __builtin_nontemporal_store(kv, &O4[t * 256]);
    float p = qf.x * kv.x + qf.y * kv.y + qf.z * kv.z + qf.w * kv.w;
    p += __shfl_xor(p, 1);
    p += __shfl_xor(p, 2);
    p += __shfl_xor(p, 4);
    p += __shfl_xor(p, 8);
    if (l16 == 0 && j <= lp) s[j] = p * 0.125f;
  }
}

// ---------------------------------------------------------------------------
// softmax over scores[bh][0..last_pos] in place; also zeroes attn[bh][:].
// ---------------------------------------------------------------------------
__global__ __launch_bounds__(256) void softmax_k(
    float* __restrict__ scores, const int* __restrict__ last_pos,
    float* __restrict__ attn) {
  int bh = blockIdx.x;
  int b = bh >> 5;
  int n = last_pos[b] + 1;
  float* s = scores + (size_t)bh * SKV;
  int tid = threadIdx.x;
  if (tid < HDIM) attn[bh * HDIM + tid] = 0.f;
  __shared__ float red[4], red2[4];
  float m = -1e30f;
  for (int j = tid; j < n; j += 256) m = fmaxf(m, s[j]);
#pragma unroll
  for (int o = 1; o < 64; o <<= 1) m = fmaxf(m, __shfl_xor(m, o));
  if ((tid & 63) == 0) red[tid >> 6] = m;
  __syncthreads();
  m = fmaxf(fmaxf(red[0], red[1]), fmaxf(red[2], red[3]));
  float sum = 0.f;
  for (int j = tid; j < n; j += 256) {
    float e = __expf(s[j] - m);
    s[j] = e;
    sum += e;
  }
#pragma unroll
  for (int o = 1; o < 64; o <<= 1) sum += __shfl_xor(sum, o);
  if ((tid & 63) == 0) red2[tid >> 6] = sum;
  __syncthreads();
  sum = red2[0] + red2[1] + red2[2] + red2[3];
  float inv = 1.f / sum;
  for (int j = tid; j < n; j += 256) s[j] *= inv;
}

// ---------------------------------------------------------------------------
// V copy + PV accumulate (unrolled, nontemporal streams).
// ---------------------------------------------------------------------------
__global__ __launch_bounds__(256) void v_copy_pv(
    const float* __restrict__ cacheV, const float* __restrict__ vnew,
    const float* __restrict__ probs, const int* __restrict__ last_pos,
    float* __restrict__ outV, float* __restrict__ attn) {
  __shared__ float part[4][64];
  int bh = blockIdx.x >> 4;
  int j0 = (blockIdx.x & 15) << 8;
  int b = bh >> 5;
  int lp = last_pos[b];
  int tid = threadIdx.x;
  int wave = tid >> 6, lane = tid & 63, q4 = lane >> 4, l16 = lane & 15;
  int rbase = wave * 4 + q4;
  const f4 vn = ((const f4*)(vnew + bh * HDIM))[l16];
  size_t base = ((size_t)bh * SKV + j0 + rbase) * 16 + l16;
  const f4* V4 = (const f4*)cacheV + base;
  f4* O4 = (f4*)outV + base;
  const float* pr = probs + (size_t)bh * SKV;
  f4 acc = (f4)0.f;
#pragma unroll
  for (int t = 0; t < 16; ++t) {
    int j = j0 + rbase + t * 16;
    f4 vv = __builtin_nontemporal_load(&V4[t * 256]);
    if (j == lp) vv = vn;
    __builtin_nontemporal_store(vv, &O4[t * 256]);
    if (j <= lp) {
      float p = pr[j];
      acc += p * vv;
    }
  }
  acc.x += __shfl_xor(acc.x, 16); acc.x += __shfl_xor(acc.x, 32);
  acc.y += __shfl_xor(acc.y, 16); acc.y += __shfl_xor(acc.y, 32);
  acc.z += __shfl_xor(acc.z, 16); acc.z += __shfl_xor(acc.z, 32);
  acc.w += __shfl_xor(acc.w, 16); acc.w += __shfl_xor(acc.w, 32);
  if (q4 == 0) ((f4*)part[wave])[l16] = acc;
  __syncthreads();
  if (tid < 64) {
    float v0 = part[0][tid] + part[1][tid] + part[2][tid] + part[3][tid];
    atomicAdd(&attn[bh * HDIM + tid], v0);
  }
}

// ---------------------------------------------------------------------------
extern "C" void kernel_launch(void* const* d_in, const int* in_sizes, int n_in,
                              void* d_out, int out_size, void* d_ws, size_t ws_size,
                              hipStream_t stream) {
  const float* x        = (const float*)d_in[0];
  const int*   last_pos = (const int*)d_in[1];
  // d_in[2] = mask (recomputed from last_pos, ignored)
  const float* Wq = (const float*)d_in[3];
  const float* bq = (const float*)d_in[4];
  const float* Wk = (const float*)d_in[5];
  const float* bk = (const float*)d_in[6];
  const float* Wv = (const float*)d_in[7];
  const float* bv = (const float*)d_in[8];
  const float* Wo = (const float*)d_in[9];
  const float* bo = (const float*)d_in[10];
  const float* cacheK = (const float*)d_in[11];
  const float* cacheV = (const float*)d_in[12];

  float* out  = (float*)d_out;                      // 32768
  float* outK = out + (size_t)BB * DMODEL;
  float* outV = outK + (size_t)BH * SKV * HDIM;

  float* ws   = (float*)d_ws;
  float* q    = ws;                                 // 32768
  float* k    = ws + 32768;
  float* v    = ws + 65536;
  float* attn = ws + 98304;
  float* big  = ws + 131072;                        // 3,145,728 floats shared region
  float* scores = big;                              // 2,097,152 (k_copy..v_copy)
  float* pq = big;                                  // 1,048,576 (gemm_part..reduce)
  float* pk = big + 1048576;
  float* pv = big + 2097152;
  float* po = big;                                  // 1,048,576 (after v_copy)

  gemm_part<<<dim3(2, 32, 3), 256, 0, stream>>>(x, Wq, Wk, Wv, pq, pk, pv, 64);
  gemm_reduce<<<dim3(128, 3), 256, 0, stream>>>(pq, pk, pv, bq, bk, bv, q, k, v, 32);
  k_copy_scores<<<8192, 256, 0, stream>>>(cacheK, k, q, last_pos, outK, scores);
  softmax_k<<<512, 256, 0, stream>>>(scores, last_pos, attn);
  v_copy_pv<<<8192, 256, 0, stream>>>(cacheV, v, scores, last_pos, outV, attn);
  gemm_part<<<dim3(2, 32, 1), 256, 0, stream>>>(attn, Wo, Wo, Wo, po, po, po, 64);
  gemm_reduce<<<dim3(128, 1), 256, 0, stream>>>(po, po, po, bo, bo, bo, out, out, out, 32);
}

// Round 4
// 445.754 us; speedup vs baseline: 1.2156x; 1.0278x over previous
//
#include <hip/hip_runtime.h>
#include <math.h>

#define BB 16
#define DMODEL 2048
#define NHEAD 32
#define SKV 4096
#define HDIM 64
#define BH (BB*NHEAD) /* 512 */

typedef float f4 __attribute__((ext_vector_type(4)));

// ---------------------------------------------------------------------------
// partial GEMM: part[tile_y][b][o] = sum_{i in tile of 64} src[b][i]*W[i][o]
// grid (2, 32, nmat), block 256, thread owns 4 consecutive o-columns.
// ---------------------------------------------------------------------------
__global__ __launch_bounds__(256) void gemm_part(
    const float* __restrict__ src,
    const float* __restrict__ Wa, const float* __restrict__ Wb,
    const float* __restrict__ Wc,
    float* __restrict__ pa, float* __restrict__ pb, float* __restrict__ pc) {
  const float* W = (blockIdx.z == 0) ? Wa : ((blockIdx.z == 1) ? Wb : Wc);
  float* part    = (blockIdx.z == 0) ? pa : ((blockIdx.z == 1) ? pb : pc);
  __shared__ float xs[16][64];
  int tid = threadIdx.x;
  int i0 = blockIdx.y * 64;
  int o  = blockIdx.x * 1024 + tid * 4;
  {
    int t = tid * 4;
    int b = t >> 6, i = t & 63;
    *(f4*)&xs[b][i] = *(const f4*)&src[b * DMODEL + i0 + i];
  }
  __syncthreads();
  f4 acc[16];
#pragma unroll
  for (int b = 0; b < 16; ++b) acc[b] = (f4)0.f;
#pragma unroll 8
  for (int i = 0; i < 64; ++i) {
    f4 w = *(const f4*)&W[(size_t)(i0 + i) * DMODEL + o];
#pragma unroll
    for (int b = 0; b < 16; ++b) acc[b] += xs[b][i] * w;
  }
  float* p = part + (size_t)blockIdx.y * (16 * DMODEL) + o;
#pragma unroll
  for (int b = 0; b < 16; ++b) *(f4*)&p[b * DMODEL] = acc[b];
}

// ---------------------------------------------------------------------------
// reduce partials over 32 tiles + bias -> dst; y==0 blocks also zero zbuf.
// grid (128, nmat)
// ---------------------------------------------------------------------------
__global__ __launch_bounds__(256) void gemm_reduce(
    const float* __restrict__ pa, const float* __restrict__ pb,
    const float* __restrict__ pc,
    const float* __restrict__ ba, const float* __restrict__ bb,
    const float* __restrict__ bc,
    float* __restrict__ da, float* __restrict__ db, float* __restrict__ dc,
    float* __restrict__ zbuf) {
  const float* p    = (blockIdx.y == 0) ? pa : ((blockIdx.y == 1) ? pb : pc);
  const float* bias = (blockIdx.y == 0) ? ba : ((blockIdx.y == 1) ? bb : bc);
  float* dst        = (blockIdx.y == 0) ? da : ((blockIdx.y == 1) ? db : dc);
  int idx = blockIdx.x * 256 + threadIdx.x;
  if (zbuf && blockIdx.y == 0) zbuf[idx] = 0.f;
  float s = bias[idx & (DMODEL - 1)];
#pragma unroll 8
  for (int t = 0; t < 32; ++t) s += p[(size_t)t * (16 * DMODEL) + idx];
  dst[idx] = s;
}

// ---------------------------------------------------------------------------
// K copy + scores + per-block softmax partials (max, sumexp).
// Block = 256 rows of one (b,h); wave = 4 rows x 16 lanes x f4.
// ---------------------------------------------------------------------------
__global__ __launch_bounds__(256) void k_copy_scores(
    const float* __restrict__ cacheK, const float* __restrict__ knew,
    const float* __restrict__ qv, const int* __restrict__ last_pos,
    float* __restrict__ outK, float* __restrict__ scores,
    float* __restrict__ pstat) {
  int bh = blockIdx.x >> 4;
  int blk = blockIdx.x & 15;
  int j0 = blk << 8;
  int b = bh >> 5;
  int lp = last_pos[b];
  int tid = threadIdx.x;
  int wave = tid >> 6, lane = tid & 63, q4 = lane >> 4, l16 = lane & 15;
  int rbase = wave * 4 + q4;
  const f4 qf = ((const f4*)(qv + bh * HDIM))[l16];
  const f4 kn = ((const f4*)(knew + bh * HDIM))[l16];
  size_t base = ((size_t)bh * SKV + j0 + rbase) * 16 + l16;
  const f4* K4 = (const f4*)cacheK + base;
  f4* O4 = (f4*)outK + base;
  float* s = scores + (size_t)bh * SKV;
  float fv[16];
#pragma unroll
  for (int t = 0; t < 16; ++t) {
    int j = j0 + rbase + t * 16;
    f4 kv = __builtin_nontemporal_load(&K4[t * 256]);
    if (j == lp) kv = kn;
    __builtin_nontemporal_store(kv, &O4[t * 256]);
    float p = qf.x * kv.x + qf.y * kv.y + qf.z * kv.z + qf.w * kv.w;
    p += __shfl_xor(p, 1);
    p += __shfl_xor(p, 2);
    p += __shfl_xor(p, 4);
    p += __shfl_xor(p, 8);
    p *= 0.125f;
    bool valid = (j <= lp);
    if (l16 == 0 && valid) s[j] = p;
    fv[t] = valid ? p : -1e30f;
  }
  float m = fv[0];
#pragma unroll
  for (int t = 1; t < 16; ++t) m = fmaxf(m, fv[t]);
  m = fmaxf(m, __shfl_xor(m, 16));
  m = fmaxf(m, __shfl_xor(m, 32));
  float se = 0.f;
#pragma unroll
  for (int t = 0; t < 16; ++t) se += __expf(fv[t] - m);
  se += __shfl_xor(se, 16);
  se += __shfl_xor(se, 32);
  __shared__ float lm[4], ls[4];
  if (lane == 0) { lm[wave] = m; ls[wave] = se; }
  __syncthreads();
  if (tid == 0) {
    float M = fmaxf(fmaxf(lm[0], lm[1]), fmaxf(lm[2], lm[3]));
    float S = ls[0] * __expf(lm[0] - M) + ls[1] * __expf(lm[1] - M)
            + ls[2] * __expf(lm[2] - M) + ls[3] * __expf(lm[3] - M);
    pstat[(bh * 16 + blk) * 2 + 0] = M;
    pstat[(bh * 16 + blk) * 2 + 1] = S;
  }
}

// ---------------------------------------------------------------------------
// V copy + PV accumulate. Prelude combines the 16 softmax partials (cheap,
// redundant per block) and stages this block's 256 probs in LDS.
// ---------------------------------------------------------------------------
__global__ __launch_bounds__(256) void v_copy_pv(
    const float* __restrict__ cacheV, const float* __restrict__ vnew,
    const float* __restrict__ scores, const float* __restrict__ pstat,
    const int* __restrict__ last_pos,
    float* __restrict__ outV, float* __restrict__ attn) {
  __shared__ float sm[16], ss[16], sp[256];
  __shared__ float part[4][64];
  int bh = blockIdx.x >> 4;
  int j0 = (blockIdx.x & 15) << 8;
  int b = bh >> 5;
  int lp = last_pos[b];
  int tid = threadIdx.x;
  if (tid < 16) {
    sm[tid] = pstat[(bh * 16 + tid) * 2 + 0];
    ss[tid] = pstat[(bh * 16 + tid) * 2 + 1];
  }
  __syncthreads();
  float M = sm[0];
#pragma unroll
  for (int i = 1; i < 16; ++i) M = fmaxf(M, sm[i]);
  float S = 0.f;
#pragma unroll
  for (int i = 0; i < 16; ++i) S += ss[i] * __expf(sm[i] - M);
  float inv = 1.f / S;
  int jj = j0 + tid;
  sp[tid] = (jj <= lp) ? __expf(scores[(size_t)bh * SKV + jj] - M) * inv : 0.f;
  __syncthreads();

  int wave = tid >> 6, lane = tid & 63, q4 = lane >> 4, l16 = lane & 15;
  int rbase = wave * 4 + q4;
  const f4 vn = ((const f4*)(vnew + bh * HDIM))[l16];
  size_t base = ((size_t)bh * SKV + j0 + rbase) * 16 + l16;
  const f4* V4 = (const f4*)cacheV + base;
  f4* O4 = (f4*)outV + base;
  f4 acc = (f4)0.f;
#pragma unroll
  for (int t = 0; t < 16; ++t) {
    int j = j0 + rbase + t * 16;
    f4 vv = __builtin_nontemporal_load(&V4[t * 256]);
    if (j == lp) vv = vn;
    __builtin_nontemporal_store(vv, &O4[t * 256]);
    acc += sp[rbase + t * 16] * vv;
  }
  acc.x += __shfl_xor(acc.x, 16); acc.x += __shfl_xor(acc.x, 32);
  acc.y += __shfl_xor(acc.y, 16); acc.y += __shfl_xor(acc.y, 32);
  acc.z += __shfl_xor(acc.z, 16); acc.z += __shfl_xor(acc.z, 32);
  acc.w += __shfl_xor(acc.w, 16); acc.w += __shfl_xor(acc.w, 32);
  if (q4 == 0) ((f4*)part[wave])[l16] = acc;
  __syncthreads();
  if (tid < 64) {
    float v0 = part[0][tid] + part[1][tid] + part[2][tid] + part[3][tid];
    atomicAdd(&attn[bh * HDIM + tid], v0);
  }
}

// ---------------------------------------------------------------------------
extern "C" void kernel_launch(void* const* d_in, const int* in_sizes, int n_in,
                              void* d_out, int out_size, void* d_ws, size_t ws_size,
                              hipStream_t stream) {
  const float* x        = (const float*)d_in[0];
  const int*   last_pos = (const int*)d_in[1];
  // d_in[2] = mask (recomputed from last_pos, ignored)
  const float* Wq = (const float*)d_in[3];
  const float* bq = (const float*)d_in[4];
  const float* Wk = (const float*)d_in[5];
  const float* bk = (const float*)d_in[6];
  const float* Wv = (const float*)d_in[7];
  const float* bv = (const float*)d_in[8];
  const float* Wo = (const float*)d_in[9];
  const float* bo = (const float*)d_in[10];
  const float* cacheK = (const float*)d_in[11];
  const float* cacheV = (const float*)d_in[12];

  float* out  = (float*)d_out;                      // 32768
  float* outK = out + (size_t)BB * DMODEL;
  float* outV = outK + (size_t)BH * SKV * HDIM;

  float* ws    = (float*)d_ws;
  float* q     = ws;                                // 32768
  float* k     = ws + 32768;
  float* v     = ws + 65536;
  float* attn  = ws + 98304;                        // 32768
  float* pstat = ws + 131072;                       // BH*16*2 = 16384
  float* big   = ws + 147456;                       // 3,145,728-float region
  float* pq = big;                                  // 32 tiles x 32768
  float* pk = big + 1048576;
  float* pv = big + 2097152;
  float* scores = big;                              // reuse after gemm_reduce
  float* po = big;                                  // reuse after v_copy

  gemm_part<<<dim3(2, 32, 3), 256, 0, stream>>>(x, Wq, Wk, Wv, pq, pk, pv);
  gemm_reduce<<<dim3(128, 3), 256, 0, stream>>>(pq, pk, pv, bq, bk, bv, q, k, v, attn);
  k_copy_scores<<<8192, 256, 0, stream>>>(cacheK, k, q, last_pos, outK, scores, pstat);
  v_copy_pv<<<8192, 256, 0, stream>>>(cacheV, v, scores, pstat, last_pos, outV, attn);
  gemm_part<<<dim3(2, 32, 1), 256, 0, stream>>>(attn, Wo, Wo, Wo, po, po, po);
  gemm_reduce<<<dim3(128, 1), 256, 0, stream>>>(po, po, po, bo, bo, bo, out, out, out, nullptr);
}